// Round 15
// baseline (458.749 us; speedup 1.0000x reference)
//
#include <hip/hip_runtime.h>
#include <hip/hip_bf16.h>
#include <stdint.h>

#define NN 50000
#define FF 256
#define HH 128
#define RR 16
#define EE 800000
#define CC 7
#define NB_ 30

typedef __attribute__((ext_vector_type(8))) short short8;
typedef __attribute__((ext_vector_type(4))) float f32x4;

__device__ __forceinline__ float bf2f(unsigned short u){
  union { unsigned int i; float f; } x; x.i = ((unsigned int)u) << 16; return x.f;
}
__device__ __forceinline__ unsigned short f2bf(float f){
  union { unsigned int i; float f; } x; x.f = f;
  unsigned int r = x.i + 0x7fffu + ((x.i >> 16) & 1u);
  return (unsigned short)(r >> 16);
}

__device__ __forceinline__ void gld16(const unsigned short* g, unsigned short* l){
  __builtin_amdgcn_global_load_lds(
      (const __attribute__((address_space(1))) unsigned int*)g,
      (__attribute__((address_space(3))) unsigned int*)l, 16, 0, 0);
}

// ------------- bf16 MFMA GEMM: A staged in LDS, B DIRECT from global (L2-hot) -------------
// C[M,Ncols] = A[M,K] * Bt[Ncols,K]^T. 128x128 tile, BK=64, 4 waves.
// B-fragment reads (16 rows x 64B, 4 lanes/row) are 64B-sector-coalesced from global;
// B matrices are <=1MB (L2/L1-resident), so this halves LDS-read-pipe traffic (the
// measured bottleneck: 225k of 348k cyc/CU) and halves bank conflicts.
// RASTER: 1D grid, XCD-chunked 8x16 panels.
template<bool BIAS, bool RELU, bool RASTER>
__global__ __launch_bounds__(256) void gemm_bt(
    const unsigned short* __restrict__ A0, int ldA0,
    const unsigned short* __restrict__ A1, int ldA1, int kSplit,
    const unsigned short* __restrict__ Bt,
    unsigned short* __restrict__ Cout, int ldC,
    const float* __restrict__ bias,
    int M, int K)
{
  __shared__ unsigned short Al[128*64];   // 16 KB
  const int tid  = threadIdx.x;
  const int lane = tid & 63;
  const int wid  = tid >> 6;
  const int wr   = wid >> 1, wc = wid & 1;
  int bm, bn;
  if (RASTER){
    // 6256 blocks = 8 XCD chunks x 782; panels of 8 bm x 16 bn (128 blocks)
    int idx  = blockIdx.x;
    int cidx = (idx & 7)*782 + (idx >> 3);
    int p = cidx >> 7;
    int within = cidx & 127;
    int ph = min(8, 391 - p*8);
    bn = within / ph;
    bm = p*8 + within % ph;
  } else {
    bm = blockIdx.x; bn = blockIdx.y;
  }

  f32x4 acc[4][4];
  #pragma unroll
  for (int m=0;m<4;m++)
    #pragma unroll
    for (int n=0;n<4;n++) acc[m][n] = (f32x4){0.f,0.f,0.f,0.f};

  // per-lane B base: row = bn*128 + wc*64 + (lane&15), k-chunk = (lane>>4)*8
  const unsigned short* bbase = Bt + (size_t)(bn*128 + wc*64 + (lane&15))*K + (lane>>4)*8;

  const int nkt = K >> 6;
  for (int kt=0; kt<nkt; ++kt){
    int c0 = kt*64;
    const unsigned short* Asrc = A0; int lda = ldA0;
    if (c0 >= kSplit){ Asrc = A1; lda = ldA1; c0 -= kSplit; }
    const unsigned short* arow = Asrc + (size_t)(bm*128 + wid*32 + (lane>>3))*lda + c0 + (lane&7)*8;
    #pragma unroll
    for (int i=0;i<4;i++)
      gld16(arow + (size_t)i*8*lda, &Al[(wid*32 + i*8)*64]);
    __syncthreads();
    #pragma unroll
    for (int ks=0; ks<2; ++ks){
      short8 a[4], b[4];
      #pragma unroll
      for (int m=0;m<4;m++)
        a[m] = *(const short8*)&Al[(wr*64 + m*16 + (lane&15))*64 + ks*32 + (lane>>4)*8];
      #pragma unroll
      for (int n=0;n<4;n++)
        b[n] = *(const short8*)(bbase + (size_t)(n*16)*K + kt*64 + ks*32);
      // swapped operands: acc = (A.B^T)^T fragment
      #pragma unroll
      for (int m=0;m<4;m++)
        #pragma unroll
        for (int n=0;n<4;n++)
          acc[m][n] = __builtin_amdgcn_mfma_f32_16x16x32_bf16(b[n], a[m], acc[m][n], 0, 0, 0);
    }
    __syncthreads();
  }

  // epilogue: row = lane&15, cols = (lane>>4)*4 + j  -> one 8B store per (m,n)
  #pragma unroll
  for (int m=0;m<4;m++){
    int row = bm*128 + wr*64 + m*16 + (lane&15);
    if (row < M){
      #pragma unroll
      for (int n=0;n<4;n++){
        int col = bn*128 + wc*64 + n*16 + ((lane>>4)<<2);
        float v0 = acc[m][n][0], v1 = acc[m][n][1], v2 = acc[m][n][2], v3 = acc[m][n][3];
        if (BIAS){ v0 += bias[col]; v1 += bias[col+1]; v2 += bias[col+2]; v3 += bias[col+3]; }
        if (RELU){ v0 = fmaxf(v0,0.f); v1 = fmaxf(v1,0.f); v2 = fmaxf(v2,0.f); v3 = fmaxf(v3,0.f); }
        unsigned int lo = (unsigned int)f2bf(v0) | ((unsigned int)f2bf(v1) << 16);
        unsigned int hi = (unsigned int)f2bf(v2) | ((unsigned int)f2bf(v3) << 16);
        *(uint2*)&Cout[(size_t)row*ldC + col] = make_uint2(lo, hi);
      }
    }
  }
}

// ------------- small-N GEMM: 64x128 tile, A in LDS, B direct from global -------------
// C[M,128] = A[M,K] * Bt[128,K]^T with 3-way column-split A = [A0|A1|A2].
// 782 blocks; 16KB LDS (Al 8KB; FHEAD reuses 16KB for hidden tile).
template<bool FHEAD>
__global__ __launch_bounds__(256) void gemm_small(
    const unsigned short* __restrict__ A0, int ldA0, int k0,
    const unsigned short* __restrict__ A1, int ldA1, int k1,
    const unsigned short* __restrict__ A2, int ldA2,
    const unsigned short* __restrict__ Bt,
    unsigned short* __restrict__ Cout,
    const float* __restrict__ bias,
    int M, int K,
    const float* __restrict__ fc_w, const float* __restrict__ fc_b,
    float* __restrict__ fout)
{
  __shared__ unsigned short smem[64*128];   // 16 KB (Al uses 8KB; Hu uses all)
  unsigned short* Al = smem;                // [64][64]
  const int lane = threadIdx.x & 63;
  const int wid  = threadIdx.x >> 6;
  const int wr   = wid >> 1, wc = wid & 1;
  const int bm   = blockIdx.x;

  f32x4 acc[2][4];
  #pragma unroll
  for (int m=0;m<2;m++)
    #pragma unroll
    for (int n=0;n<4;n++) acc[m][n] = (f32x4){0.f,0.f,0.f,0.f};

  const unsigned short* bbase = Bt + (size_t)(wc*64 + (lane&15))*K + (lane>>4)*8;

  const int nkt = K >> 6;
  for (int kt=0; kt<nkt; ++kt){
    int c0 = kt*64;
    const unsigned short* Asrc; int lda;
    if (c0 < k0){ Asrc = A0; lda = ldA0; }
    else if (c0 < k0 + k1){ Asrc = A1; lda = ldA1; c0 -= k0; }
    else { Asrc = A2; lda = ldA2; c0 -= (k0 + k1); }
    const unsigned short* arow = Asrc + (size_t)(bm*64 + wid*16 + (lane>>3))*lda + c0 + (lane&7)*8;
    gld16(arow,                 &Al[(wid*16    )*64]);
    gld16(arow + (size_t)8*lda, &Al[(wid*16 + 8)*64]);
    __syncthreads();
    #pragma unroll
    for (int ks=0; ks<2; ++ks){
      short8 a[2], b[4];
      #pragma unroll
      for (int m=0;m<2;m++)
        a[m] = *(const short8*)&Al[(wr*32 + m*16 + (lane&15))*64 + ks*32 + (lane>>4)*8];
      #pragma unroll
      for (int n=0;n<4;n++)
        b[n] = *(const short8*)(bbase + (size_t)(n*16)*K + kt*64 + ks*32);
      #pragma unroll
      for (int m=0;m<2;m++)
        #pragma unroll
        for (int n=0;n<4;n++)
          acc[m][n] = __builtin_amdgcn_mfma_f32_16x16x32_bf16(b[n], a[m], acc[m][n], 0, 0, 0);
    }
    __syncthreads();
  }

  if (FHEAD){
    // hidden tile (relu(..+bias)) -> LDS, swizzled pair index (verified R8 logic)
    unsigned int* Hu = (unsigned int*)smem;    // [64 rows][64 uint pairs]
    #pragma unroll
    for (int m=0;m<2;m++){
      int row = wr*32 + m*16 + (lane&15);
      #pragma unroll
      for (int n=0;n<4;n++){
        int cbase = wc*64 + n*16 + ((lane>>4)<<2);
        float v0 = fmaxf(acc[m][n][0] + bias[cbase],   0.f);
        float v1 = fmaxf(acc[m][n][1] + bias[cbase+1], 0.f);
        float v2 = fmaxf(acc[m][n][2] + bias[cbase+2], 0.f);
        float v3 = fmaxf(acc[m][n][3] + bias[cbase+3], 0.f);
        int cp = (cbase>>1) ^ ((row&7)<<1);
        Hu[row*64 + cp    ] = (unsigned int)f2bf(v0) | ((unsigned int)f2bf(v1) << 16);
        Hu[row*64 + cp + 1] = (unsigned int)f2bf(v2) | ((unsigned int)f2bf(v3) << 16);
      }
    }
    __syncthreads();
    float w0[CC], w1[CC];
    #pragma unroll
    for (int c=0;c<CC;c++){
      w0[c] = fc_w[(lane*2)*CC + c];
      w1[c] = fc_w[(lane*2+1)*CC + c];
    }
    for (int i=0;i<16;i++){
      int r = wid*16 + i;
      int node = bm*64 + r;
      if (node >= NN) break;
      unsigned int h = Hu[r*64 + (lane ^ ((r&7)<<1))];
      float h0 = bf2f((unsigned short)h);
      float h1 = bf2f((unsigned short)(h>>16));
      float lg[CC];
      #pragma unroll
      for (int c=0;c<CC;c++){
        float p = h0*w0[c] + h1*w1[c];
        #pragma unroll
        for (int off=32; off; off>>=1) p += __shfl_down(p, off, 64);
        lg[c] = p;
      }
      if (lane == 0){
        float l[CC]; float mx = -1e30f;
        #pragma unroll
        for (int c=0;c<CC;c++){ l[c] = lg[c] + fc_b[c]; mx = fmaxf(mx, l[c]); }
        float s = 0.f;
        #pragma unroll
        for (int c=0;c<CC;c++) s += expf(l[c]-mx);
        float lse = logf(s);
        #pragma unroll
        for (int c=0;c<CC;c++) fout[(size_t)node*CC + c] = l[c] - mx - lse;
      }
    }
    return;
  }

  // epilogue (bias, no relu): packed 8B stores
  #pragma unroll
  for (int m=0;m<2;m++){
    int row = bm*64 + wr*32 + m*16 + (lane&15);
    if (row < M){
      #pragma unroll
      for (int n=0;n<4;n++){
        int col = wc*64 + n*16 + ((lane>>4)<<2);
        float v0 = acc[m][n][0] + bias[col];
        float v1 = acc[m][n][1] + bias[col+1];
        float v2 = acc[m][n][2] + bias[col+2];
        float v3 = acc[m][n][3] + bias[col+3];
        unsigned int lo = (unsigned int)f2bf(v0) | ((unsigned int)f2bf(v1) << 16);
        unsigned int hi = (unsigned int)f2bf(v2) | ((unsigned int)f2bf(v3) << 16);
        *(uint2*)&Cout[(size_t)row*HH + col] = make_uint2(lo, hi);
      }
    }
  }
}

// ---------------- small prep kernels ----------------
__global__ void k_cvt(const float* __restrict__ in, unsigned short* __restrict__ out, int n4){
  int i = blockIdx.x*256 + threadIdx.x;
  if (i >= n4) return;
  float4 v = ((const float4*)in)[i];
  union { unsigned short u[4]; uint2 q; } t;
  t.u[0]=f2bf(v.x); t.u[1]=f2bf(v.y); t.u[2]=f2bf(v.z); t.u[3]=f2bf(v.w);
  ((uint2*)out)[i] = t.q;
}

// WT[(r*128+o)][i] = sum_b comp[r,b]*basis[b,i,o] ; coalesced reads + LDS transpose
__global__ __launch_bounds__(256) void k_build_wt(const float* __restrict__ comp,
                                                  const float* __restrict__ basis,
                                                  unsigned short* __restrict__ WT){
  __shared__ float sm[16][129];
  __shared__ float cmp[NB_];
  int r = blockIdx.x >> 4, i0 = (blockIdx.x & 15)*16;
  int o = threadIdx.x & 127, ih = threadIdx.x >> 7;
  if (threadIdx.x < NB_) cmp[threadIdx.x] = comp[r*NB_ + threadIdx.x];
  __syncthreads();
  #pragma unroll
  for (int step=0; step<8; ++step){
    int i = i0 + step*2 + ih;
    float s = 0.f;
    #pragma unroll 6
    for (int b=0;b<NB_;b++) s += cmp[b]*basis[((size_t)b*FF + i)*HH + o];
    sm[step*2+ih][o] = s;
  }
  __syncthreads();
  #pragma unroll
  for (int w=0;w<8;w++){
    int o2 = w*16 + (threadIdx.x>>4);
    int ii = threadIdx.x & 15;
    WT[((size_t)(r*128 + o2))*FF + i0 + ii] = f2bf(sm[ii][o2]);
  }
}

// outT[o][k] = in0[k*128+o]    (bf16 B^T builder, rootT)
__global__ void k_transpose_cat(const float* __restrict__ in0, int k0,
                                unsigned short* __restrict__ outT){
  int idx = blockIdx.x*256 + threadIdx.x;
  if (idx >= 128*k0) return;
  int o = idx / k0, k = idx % k0;
  outT[idx] = f2bf(in0[(size_t)k*HH + o]);
}

// Fused final-GEMM weights: BtF[o][0:256]=lin_x^T; [256:384]=(w_rel@lin_o)^T;
// [384:512]=(w_root@lin_o)^T.  biasF = bias2@lin_o + lin_b.
__global__ __launch_bounds__(256) void k_fuse_w(const float* __restrict__ w_rel,
                                                const float* __restrict__ w_root,
                                                const float* __restrict__ lin_w,
                                                const float* __restrict__ lin_b,
                                                const float* __restrict__ bias2,
                                                unsigned short* __restrict__ BtF,
                                                float* __restrict__ biasF){
  int o = blockIdx.x;        // 0..127
  int t = threadIdx.x;       // 0..255
  BtF[(size_t)o*512 + t] = f2bf(lin_w[(size_t)t*HH + o]);
  const float* Wsrc = (t < 128) ? w_rel : w_root;
  int k = t & 127;
  float s = 0.f;
  #pragma unroll 4
  for (int j=0;j<128;j++) s += Wsrc[k*128 + j] * lin_w[(size_t)(256+j)*HH + o];
  BtF[(size_t)o*512 + 256 + ((t<128)?0:128) + k] = f2bf(s);
  if (blockIdx.x == 0 && t < 128){
    float b = lin_b[t];
    for (int j=0;j<128;j++) b += bias2[j] * lin_w[(size_t)(256+j)*HH + t];
    biasF[t] = b;
  }
}

// ---------------- CSR by dst ----------------
__global__ void k_count(const int* __restrict__ dstv, int* __restrict__ counts){
  int e = blockIdx.x*256 + threadIdx.x;
  if (e >= EE) return;
  atomicAdd(&counts[dstv[e]], 1);
}

__global__ __launch_bounds__(256) void k_scan1(const int* __restrict__ counts,
                                               int* __restrict__ row_ptr,
                                               int* __restrict__ blocksum){
  __shared__ int wsum[4];
  int g = blockIdx.x*256 + threadIdx.x;
  int lane = threadIdx.x & 63, wv = threadIdx.x >> 6;
  int v = (g < NN) ? counts[g] : 0;
  int s = v;
  #pragma unroll
  for (int off=1; off<64; off<<=1){ int t = __shfl_up(s, off, 64); if (lane>=off) s += t; }
  if (lane==63) wsum[wv] = s;
  __syncthreads();
  int wo = 0;
  #pragma unroll
  for (int i=0;i<4;i++) if (i < wv) wo += wsum[i];
  int incl = s + wo;
  if (g < NN) row_ptr[g] = incl - v;
  if (threadIdx.x == 255) blocksum[blockIdx.x] = incl;
}
__global__ __launch_bounds__(256) void k_scan2(int* __restrict__ blocksum, int nb){
  __shared__ int wsum[4];
  int t = threadIdx.x, lane = t & 63, wv = t >> 6;
  int v = (t < nb) ? blocksum[t] : 0;
  int s = v;
  #pragma unroll
  for (int off=1; off<64; off<<=1){ int u = __shfl_up(s, off, 64); if (lane>=off) s += u; }
  if (lane==63) wsum[wv] = s;
  __syncthreads();
  int wo = 0;
  #pragma unroll
  for (int i=0;i<4;i++) if (i < wv) wo += wsum[i];
  if (t < nb) blocksum[t] = s + wo - v;
}
__global__ __launch_bounds__(256) void k_scan3(int* __restrict__ row_ptr,
                                               const int* __restrict__ blocksum){
  int g = blockIdx.x*256 + threadIdx.x;
  if (g < NN) row_ptr[g] += blocksum[blockIdx.x];
  if (g == 0) row_ptr[NN] = EE;
}

__global__ void k_fill(const int* __restrict__ srcv, const int* __restrict__ dstv,
                       const int* __restrict__ etv, const int* __restrict__ row_ptr,
                       int* __restrict__ cursor, int* __restrict__ packed){
  int e = blockIdx.x*256 + threadIdx.x;
  if (e >= EE) return;
  int d = dstv[e];
  int p = atomicAdd(&cursor[d], 1);
  packed[row_ptr[d] + p] = (srcv[e] & 0xffff) | (etv[e] << 16);
}

// ---- RGCN aggregate: wave-per-node, uint loads (256B/wave/edge), 8-edge ILP ----
__global__ __launch_bounds__(256) void k_agg1(const int* __restrict__ row_ptr,
                                              const int* __restrict__ packed,
                                              const unsigned int* __restrict__ xWu,
                                              unsigned int* __restrict__ out1u){
  __shared__ int   cnt[4][RR];
  __shared__ float inv[4][RR];
  const int lane = threadIdx.x & 63;
  const int wv   = threadIdx.x >> 6;
  const int node = blockIdx.x*4 + wv;          // grid exactly covers NN
  if (lane < RR) cnt[wv][lane] = 0;
  __syncthreads();
  const int b0 = row_ptr[node], b1 = row_ptr[node+1];
  for (int j=b0+lane; j<b1; j+=64) atomicAdd(&cnt[wv][(packed[j]>>16)&15], 1);
  __syncthreads();
  if (lane < RR) inv[wv][lane] = 1.0f / fmaxf((float)cnt[wv][lane], 1.0f);
  __syncthreads();

  float a0=0.f, a1=0.f;
  int j = b0;
  for (; j+8 <= b1; j+=8){
    int pv[8]; unsigned int vv[8];
    #pragma unroll
    for (int q=0;q<8;q++) pv[q] = packed[j+q];
    #pragma unroll
    for (int q=0;q<8;q++)
      vv[q] = xWu[((size_t)(((pv[q]&0xffff)<<4)|((pv[q]>>16)&15)) << 6) + lane];
    #pragma unroll
    for (int q=0;q<8;q++){
      float f = inv[wv][(pv[q]>>16)&15];
      a0 += bf2f((unsigned short)vv[q])*f;
      a1 += bf2f((unsigned short)(vv[q]>>16))*f;
    }
  }
  for (; j+4 <= b1; j+=4){
    int pv[4]; unsigned int vv[4];
    #pragma unroll
    for (int q=0;q<4;q++) pv[q] = packed[j+q];
    #pragma unroll
    for (int q=0;q<4;q++)
      vv[q] = xWu[((size_t)(((pv[q]&0xffff)<<4)|((pv[q]>>16)&15)) << 6) + lane];
    #pragma unroll
    for (int q=0;q<4;q++){
      float f = inv[wv][(pv[q]>>16)&15];
      a0 += bf2f((unsigned short)vv[q])*f;
      a1 += bf2f((unsigned short)(vv[q]>>16))*f;
    }
  }
  for (; j<b1; ++j){
    int p = packed[j];
    unsigned int v = xWu[((size_t)(((p&0xffff)<<4)|((p>>16)&15)) << 6) + lane];
    float f = inv[wv][(p>>16)&15];
    a0 += bf2f((unsigned short)v)*f;
    a1 += bf2f((unsigned short)(v>>16))*f;
  }
  size_t o = (size_t)node*64 + lane;
  unsigned int cur = out1u[o];
  float r0 = bf2f((unsigned short)cur)       + a0;
  float r1 = bf2f((unsigned short)(cur>>16)) + a1;
  out1u[o] = (unsigned int)f2bf(r0) | ((unsigned int)f2bf(r1) << 16);
}

// ---- GraphConv aggregate: wave-per-node, sum out1[src], 8-edge ILP ----
__global__ __launch_bounds__(256) void k_agg2(const int* __restrict__ row_ptr,
                                              const int* __restrict__ packed,
                                              const unsigned int* __restrict__ out1u,
                                              unsigned int* __restrict__ agg2u){
  const int lane = threadIdx.x & 63;
  const int wv   = threadIdx.x >> 6;
  const int node = blockIdx.x*4 + wv;
  const int b0 = row_ptr[node], b1 = row_ptr[node+1];
  float a0=0.f, a1=0.f;
  int j = b0;
  for (; j+8 <= b1; j+=8){
    unsigned int vv[8];
    #pragma unroll
    for (int q=0;q<8;q++)
      vv[q] = out1u[(size_t)(packed[j+q]&0xffff)*64 + lane];
    #pragma unroll
    for (int q=0;q<8;q++){
      a0 += bf2f((unsigned short)vv[q]);
      a1 += bf2f((unsigned short)(vv[q]>>16));
    }
  }
  for (; j+4 <= b1; j+=4){
    unsigned int vv[4];
    #pragma unroll
    for (int q=0;q<4;q++)
      vv[q] = out1u[(size_t)(packed[j+q]&0xffff)*64 + lane];
    #pragma unroll
    for (int q=0;q<4;q++){
      a0 += bf2f((unsigned short)vv[q]);
      a1 += bf2f((unsigned short)(vv[q]>>16));
    }
  }
  for (; j<b1; ++j){
    unsigned int v = out1u[(size_t)(packed[j]&0xffff)*64 + lane];
    a0 += bf2f((unsigned short)v);
    a1 += bf2f((unsigned short)(v>>16));
  }
  agg2u[(size_t)node*64 + lane] = (unsigned int)f2bf(a0) | ((unsigned int)f2bf(a1) << 16);
}

extern "C" void kernel_launch(void* const* d_in, const int* in_sizes, int n_in,
                              void* d_out, int out_size, void* d_ws, size_t ws_size,
                              hipStream_t stream)
{
  const float* x      = (const float*)d_in[0];
  const int*   eidx   = (const int*)d_in[1];
  const int*   etype  = (const int*)d_in[3];
  const float* basis  = (const float*)d_in[8];
  const float* comp   = (const float*)d_in[9];
  const float* root1  = (const float*)d_in[10];
  const float* bias1  = (const float*)d_in[11];
  const float* w_rel  = (const float*)d_in[12];
  const float* w_root = (const float*)d_in[13];
  const float* bias2  = (const float*)d_in[14];
  const float* lin_w  = (const float*)d_in[15];
  const float* lin_b  = (const float*)d_in[16];
  const float* fc_w   = (const float*)d_in[17];
  const float* fc_b   = (const float*)d_in[18];
  const int* srcv = eidx;
  const int* dstv = eidx + EE;

  // workspace layout: A-source matrices padded to 50048 rows
  char* w = (char*)d_ws;
  unsigned short* x_bf    = (unsigned short*)(w + 0);                       // 50048*256*2
  unsigned short* xW      = (unsigned short*)(w + 25624576);                // 50000*2048*2 (dead after k_agg1)
  unsigned short* agg2_bf = (unsigned short*)(w + 25624576 + 12812288);     //  alias in xW (padded, 50048*128*2)
  unsigned short* WT      = (unsigned short*)(w + 230424576);               // 1,048,576
  unsigned short* rootT   = (unsigned short*)(w + 231473152);               // 65,536
  unsigned short* BtF     = (unsigned short*)(w + 231538688);               // 131,072 [128][512]
  float*          biasF   = (float*)         (w + 231669760);               // 2,048
  unsigned short* out1_bf = (unsigned short*)(w + 231702528);               // 50048*128*2 (padded)
  int*            counts  = (int*)(w + 244514816);                          // 200,192
  int*            row_ptr = (int*)(w + 244715008);                          // 200,192
  int*            cursor  = (int*)(w + 244915200);                          // 200,192
  int*            packed  = (int*)(w + 245115392);                          // 3,200,000
  int*            blocksum= (int*)(w + 248315392);                          // 1,024

  hipMemsetAsync(counts, 0, NN*4, stream);
  hipMemsetAsync(cursor, 0, NN*4, stream);

  // prep
  k_cvt<<<12500, 256, 0, stream>>>(x, x_bf, NN*FF/4);
  k_build_wt<<<256, 256, 0, stream>>>(comp, basis, WT);
  k_transpose_cat<<<128, 256, 0, stream>>>(root1, 256, rootT);
  k_fuse_w<<<128, 256, 0, stream>>>(w_rel, w_root, lin_w, lin_b, bias2, BtF, biasF);

  // CSR by dst
  k_count<<<3125, 256, 0, stream>>>(dstv, counts);
  k_scan1<<<196, 256, 0, stream>>>(counts, row_ptr, blocksum);
  k_scan2<<<1, 256, 0, stream>>>(blocksum, 196);
  k_scan3<<<196, 256, 0, stream>>>(row_ptr, blocksum);
  k_fill<<<3125, 256, 0, stream>>>(srcv, dstv, etype, row_ptr, cursor, packed);

  // GEMM1: xW = x_bf @ W  -> [N, 2048] bf16   (rasterized 1D grid: 391*16 = 6256)
  gemm_bt<false,false,true><<<6256, 256, 0, stream>>>(
      x_bf, FF, nullptr, 0, 1<<30, WT, xW, 2048, nullptr, NN, FF);
  // root: out1_bf = x_bf @ root1 + bias1  (64-row tiles, 782 blocks)
  gemm_small<false><<<782, 256, 0, stream>>>(
      x_bf, FF, 1<<30, nullptr, 0, 0, nullptr, 0,
      rootT, out1_bf, bias1, NN, FF, nullptr, nullptr, nullptr);
  // RGCN aggregate: out1_bf += mean-per-(dst,rel) messages
  k_agg1<<<12500, 256, 0, stream>>>(row_ptr, packed, (const unsigned int*)xW, (unsigned int*)out1_bf);
  // GraphConv aggregate -> agg2_bf
  k_agg2<<<12500, 256, 0, stream>>>(row_ptr, packed, (const unsigned int*)out1_bf, (unsigned int*)agg2_bf);
  // fused final GEMM (+head): d_out = log_softmax(relu([x|agg2|out1]@BtF^T + biasF) @ fc_w + fc_b)
  gemm_small<true><<<782, 256, 0, stream>>>(
      x_bf, FF, FF, agg2_bf, HH, HH, out1_bf, HH,
      BtF, nullptr, biasF, NN, 512, fc_w, fc_b, (float*)d_out);
}

// Round 16
// 407.138 us; speedup vs baseline: 1.1268x; 1.1268x over previous
//
#include <hip/hip_runtime.h>
#include <hip/hip_bf16.h>
#include <stdint.h>

#define NN 50000
#define FF 256
#define HH 128
#define RR 16
#define EE 800000
#define CC 7
#define NB_ 30

typedef __attribute__((ext_vector_type(8))) short short8;
typedef __attribute__((ext_vector_type(4))) float f32x4;

__device__ __forceinline__ float bf2f(unsigned short u){
  union { unsigned int i; float f; } x; x.i = ((unsigned int)u) << 16; return x.f;
}
__device__ __forceinline__ unsigned short f2bf(float f){
  union { unsigned int i; float f; } x; x.f = f;
  unsigned int r = x.i + 0x7fffu + ((x.i >> 16) & 1u);
  return (unsigned short)(r >> 16);
}

__device__ __forceinline__ void gld16(const unsigned short* g, unsigned short* l){
  __builtin_amdgcn_global_load_lds(
      (const __attribute__((address_space(1))) unsigned int*)g,
      (__attribute__((address_space(3))) unsigned int*)l, 16, 0, 0);
}

// ---------------- bf16 MFMA GEMM: C[M,Ncols] = A[M,K] * Bt[Ncols,K]^T ----------
// m97 structure: 128x128 tile, BK=64, 4 waves, global_load_lds staging, linear LDS.
// Swapped-operand MFMA (acc holds C^T fragment) -> each lane owns 4 consecutive
// output cols -> packed 8B stores. RASTER: 1D grid, XCD-chunked 8x16 panels.
// (Measured-best gemm1 config: 145us; 7 structural variants all regressed.)
template<bool BIAS, bool RELU, bool RASTER>
__global__ __launch_bounds__(256) void gemm_bt(
    const unsigned short* __restrict__ A0, int ldA0,
    const unsigned short* __restrict__ A1, int ldA1, int kSplit,
    const unsigned short* __restrict__ Bt,
    unsigned short* __restrict__ Cout, int ldC,
    const float* __restrict__ bias,
    int M, int K)
{
  __shared__ unsigned short Al[128*64];
  __shared__ unsigned short Bl[128*64];
  const int tid  = threadIdx.x;
  const int lane = tid & 63;
  const int wid  = tid >> 6;
  const int wr   = wid >> 1, wc = wid & 1;
  int bm, bn;
  if (RASTER){
    // 6256 blocks = 8 XCD chunks x 782; panels of 8 bm x 16 bn (128 blocks)
    int idx  = blockIdx.x;
    int cidx = (idx & 7)*782 + (idx >> 3);
    int p = cidx >> 7;
    int within = cidx & 127;
    int ph = min(8, 391 - p*8);
    bn = within / ph;
    bm = p*8 + within % ph;
  } else {
    bm = blockIdx.x; bn = blockIdx.y;
  }

  f32x4 acc[4][4];
  #pragma unroll
  for (int m=0;m<4;m++)
    #pragma unroll
    for (int n=0;n<4;n++) acc[m][n] = (f32x4){0.f,0.f,0.f,0.f};

  const int nkt = K >> 6;
  for (int kt=0; kt<nkt; ++kt){
    int c0 = kt*64;
    const unsigned short* Asrc = A0; int lda = ldA0;
    if (c0 >= kSplit){ Asrc = A1; lda = ldA1; c0 -= kSplit; }
    const unsigned short* arow = Asrc + (size_t)(bm*128 + wid*32 + (lane>>3))*lda + c0 + (lane&7)*8;
    const unsigned short* brow = Bt   + (size_t)(bn*128 + wid*32 + (lane>>3))*K  + kt*64 + (lane&7)*8;
    #pragma unroll
    for (int i=0;i<4;i++){
      gld16(arow + (size_t)i*8*lda, &Al[(wid*32 + i*8)*64]);
      gld16(brow + (size_t)i*8*K,   &Bl[(wid*32 + i*8)*64]);
    }
    __syncthreads();
    #pragma unroll
    for (int ks=0; ks<2; ++ks){
      short8 a[4], b[4];
      #pragma unroll
      for (int m=0;m<4;m++)
        a[m] = *(const short8*)&Al[(wr*64 + m*16 + (lane&15))*64 + ks*32 + (lane>>4)*8];
      #pragma unroll
      for (int n=0;n<4;n++)
        b[n] = *(const short8*)&Bl[(wc*64 + n*16 + (lane&15))*64 + ks*32 + (lane>>4)*8];
      // swapped operands: acc = (A.B^T)^T fragment
      #pragma unroll
      for (int m=0;m<4;m++)
        #pragma unroll
        for (int n=0;n<4;n++)
          acc[m][n] = __builtin_amdgcn_mfma_f32_16x16x32_bf16(b[n], a[m], acc[m][n], 0, 0, 0);
    }
    __syncthreads();
  }

  // epilogue: row = lane&15, cols = (lane>>4)*4 + j  -> one 8B store per (m,n)
  #pragma unroll
  for (int m=0;m<4;m++){
    int row = bm*128 + wr*64 + m*16 + (lane&15);
    if (row < M){
      #pragma unroll
      for (int n=0;n<4;n++){
        int col = bn*128 + wc*64 + n*16 + ((lane>>4)<<2);
        float v0 = acc[m][n][0], v1 = acc[m][n][1], v2 = acc[m][n][2], v3 = acc[m][n][3];
        if (BIAS){ v0 += bias[col]; v1 += bias[col+1]; v2 += bias[col+2]; v3 += bias[col+3]; }
        if (RELU){ v0 = fmaxf(v0,0.f); v1 = fmaxf(v1,0.f); v2 = fmaxf(v2,0.f); v3 = fmaxf(v3,0.f); }
        unsigned int lo = (unsigned int)f2bf(v0) | ((unsigned int)f2bf(v1) << 16);
        unsigned int hi = (unsigned int)f2bf(v2) | ((unsigned int)f2bf(v3) << 16);
        *(uint2*)&Cout[(size_t)row*ldC + col] = make_uint2(lo, hi);
      }
    }
  }
}

// ---------------- small prep kernels ----------------
__global__ void k_cvt(const float* __restrict__ in, unsigned short* __restrict__ out, int n4){
  int i = blockIdx.x*256 + threadIdx.x;
  if (i >= n4) return;
  float4 v = ((const float4*)in)[i];
  union { unsigned short u[4]; uint2 q; } t;
  t.u[0]=f2bf(v.x); t.u[1]=f2bf(v.y); t.u[2]=f2bf(v.z); t.u[3]=f2bf(v.w);
  ((uint2*)out)[i] = t.q;
}

// WT[(r*128+o)][i] = sum_b comp[r,b]*basis[b,i,o] ; coalesced reads + LDS transpose
__global__ __launch_bounds__(256) void k_build_wt(const float* __restrict__ comp,
                                                  const float* __restrict__ basis,
                                                  unsigned short* __restrict__ WT){
  __shared__ float sm[16][129];
  __shared__ float cmp[NB_];
  int r = blockIdx.x >> 4, i0 = (blockIdx.x & 15)*16;
  int o = threadIdx.x & 127, ih = threadIdx.x >> 7;
  if (threadIdx.x < NB_) cmp[threadIdx.x] = comp[r*NB_ + threadIdx.x];
  __syncthreads();
  #pragma unroll
  for (int step=0; step<8; ++step){
    int i = i0 + step*2 + ih;
    float s = 0.f;
    #pragma unroll 6
    for (int b=0;b<NB_;b++) s += cmp[b]*basis[((size_t)b*FF + i)*HH + o];
    sm[step*2+ih][o] = s;
  }
  __syncthreads();
  #pragma unroll
  for (int w=0;w<8;w++){
    int o2 = w*16 + (threadIdx.x>>4);
    int ii = threadIdx.x & 15;
    WT[((size_t)(r*128 + o2))*FF + i0 + ii] = f2bf(sm[ii][o2]);
  }
}

// outT[o][k] = k<k0 ? in0[k*128+o] : in1[(k-k0)*128+o]    (bf16 B^T builder)
__global__ void k_transpose_cat(const float* __restrict__ in0, int k0,
                                const float* __restrict__ in1, int k1,
                                unsigned short* __restrict__ outT){
  int K = k0 + k1;
  int idx = blockIdx.x*256 + threadIdx.x;
  if (idx >= 128*K) return;
  int o = idx / K, k = idx % K;
  float v = (k < k0) ? in0[(size_t)k*HH + o] : in1[(size_t)(k-k0)*HH + o];
  outT[idx] = f2bf(v);
}

// ---------------- CSR by dst ----------------
__global__ void k_count(const int* __restrict__ dstv, int* __restrict__ counts){
  int e = blockIdx.x*256 + threadIdx.x;
  if (e >= EE) return;
  atomicAdd(&counts[dstv[e]], 1);
}

// hierarchical exclusive scan: 196 blocks x 256
__global__ __launch_bounds__(256) void k_scan1(const int* __restrict__ counts,
                                               int* __restrict__ row_ptr,
                                               int* __restrict__ blocksum){
  __shared__ int wsum[4];
  int g = blockIdx.x*256 + threadIdx.x;
  int lane = threadIdx.x & 63, wv = threadIdx.x >> 6;
  int v = (g < NN) ? counts[g] : 0;
  int s = v;
  #pragma unroll
  for (int off=1; off<64; off<<=1){ int t = __shfl_up(s, off, 64); if (lane>=off) s += t; }
  if (lane==63) wsum[wv] = s;
  __syncthreads();
  int wo = 0;
  #pragma unroll
  for (int i=0;i<4;i++) if (i < wv) wo += wsum[i];
  int incl = s + wo;
  if (g < NN) row_ptr[g] = incl - v;
  if (threadIdx.x == 255) blocksum[blockIdx.x] = incl;
}
__global__ __launch_bounds__(256) void k_scan2(int* __restrict__ blocksum, int nb){
  __shared__ int wsum[4];
  int t = threadIdx.x, lane = t & 63, wv = t >> 6;
  int v = (t < nb) ? blocksum[t] : 0;
  int s = v;
  #pragma unroll
  for (int off=1; off<64; off<<=1){ int u = __shfl_up(s, off, 64); if (lane>=off) s += u; }
  if (lane==63) wsum[wv] = s;
  __syncthreads();
  int wo = 0;
  #pragma unroll
  for (int i=0;i<4;i++) if (i < wv) wo += wsum[i];
  if (t < nb) blocksum[t] = s + wo - v;
}
__global__ __launch_bounds__(256) void k_scan3(int* __restrict__ row_ptr,
                                               const int* __restrict__ blocksum){
  int g = blockIdx.x*256 + threadIdx.x;
  if (g < NN) row_ptr[g] += blocksum[blockIdx.x];
  if (g == 0) row_ptr[NN] = EE;
}

__global__ void k_fill(const int* __restrict__ srcv, const int* __restrict__ dstv,
                       const int* __restrict__ etv, const int* __restrict__ row_ptr,
                       int* __restrict__ cursor, int* __restrict__ packed){
  int e = blockIdx.x*256 + threadIdx.x;
  if (e >= EE) return;
  int d = dstv[e];
  int p = atomicAdd(&cursor[d], 1);
  packed[row_ptr[d] + p] = (srcv[e] & 0xffff) | (etv[e] << 16);
}

// ---- RGCN aggregate: wave-per-node, uint loads (256B/wave/edge), 16-edge ILP ----
__global__ __launch_bounds__(256) void k_agg1(const int* __restrict__ row_ptr,
                                              const int* __restrict__ packed,
                                              const unsigned int* __restrict__ xWu,
                                              unsigned int* __restrict__ out1u){
  __shared__ int   cnt[4][RR];
  __shared__ float inv[4][RR];
  const int lane = threadIdx.x & 63;
  const int wv   = threadIdx.x >> 6;
  const int node = blockIdx.x*4 + wv;          // grid exactly covers NN
  if (lane < RR) cnt[wv][lane] = 0;
  __syncthreads();
  const int b0 = row_ptr[node], b1 = row_ptr[node+1];
  for (int j=b0+lane; j<b1; j+=64) atomicAdd(&cnt[wv][(packed[j]>>16)&15], 1);
  __syncthreads();
  if (lane < RR) inv[wv][lane] = 1.0f / fmaxf((float)cnt[wv][lane], 1.0f);
  __syncthreads();

  float a0=0.f, a1=0.f;
  int j = b0;
  for (; j+16 <= b1; j+=16){
    int pv[16]; unsigned int vv[16];
    #pragma unroll
    for (int q=0;q<16;q++) pv[q] = packed[j+q];
    #pragma unroll
    for (int q=0;q<16;q++)
      vv[q] = xWu[((size_t)(((pv[q]&0xffff)<<4)|((pv[q]>>16)&15)) << 6) + lane];
    #pragma unroll
    for (int q=0;q<16;q++){
      float f = inv[wv][(pv[q]>>16)&15];
      a0 += bf2f((unsigned short)vv[q])*f;
      a1 += bf2f((unsigned short)(vv[q]>>16))*f;
    }
  }
  for (; j+4 <= b1; j+=4){
    int pv[4]; unsigned int vv[4];
    #pragma unroll
    for (int q=0;q<4;q++) pv[q] = packed[j+q];
    #pragma unroll
    for (int q=0;q<4;q++)
      vv[q] = xWu[((size_t)(((pv[q]&0xffff)<<4)|((pv[q]>>16)&15)) << 6) + lane];
    #pragma unroll
    for (int q=0;q<4;q++){
      float f = inv[wv][(pv[q]>>16)&15];
      a0 += bf2f((unsigned short)vv[q])*f;
      a1 += bf2f((unsigned short)(vv[q]>>16))*f;
    }
  }
  for (; j<b1; ++j){
    int p = packed[j];
    unsigned int v = xWu[((size_t)(((p&0xffff)<<4)|((p>>16)&15)) << 6) + lane];
    float f = inv[wv][(p>>16)&15];
    a0 += bf2f((unsigned short)v)*f;
    a1 += bf2f((unsigned short)(v>>16))*f;
  }
  size_t o = (size_t)node*64 + lane;
  unsigned int cur = out1u[o];
  float r0 = bf2f((unsigned short)cur)       + a0;
  float r1 = bf2f((unsigned short)(cur>>16)) + a1;
  out1u[o] = (unsigned int)f2bf(r0) | ((unsigned int)f2bf(r1) << 16);
}

// ---- GraphConv aggregate: wave-per-node, sum out1[src], 16-edge ILP ----
__global__ __launch_bounds__(256) void k_agg2(const int* __restrict__ row_ptr,
                                              const int* __restrict__ packed,
                                              const unsigned int* __restrict__ out1u,
                                              unsigned int* __restrict__ agg2u){
  const int lane = threadIdx.x & 63;
  const int wv   = threadIdx.x >> 6;
  const int node = blockIdx.x*4 + wv;
  const int b0 = row_ptr[node], b1 = row_ptr[node+1];
  float a0=0.f, a1=0.f;
  int j = b0;
  for (; j+16 <= b1; j+=16){
    unsigned int vv[16];
    #pragma unroll
    for (int q=0;q<16;q++)
      vv[q] = out1u[(size_t)(packed[j+q]&0xffff)*64 + lane];
    #pragma unroll
    for (int q=0;q<16;q++){
      a0 += bf2f((unsigned short)vv[q]);
      a1 += bf2f((unsigned short)(vv[q]>>16));
    }
  }
  for (; j+4 <= b1; j+=4){
    unsigned int vv[4];
    #pragma unroll
    for (int q=0;q<4;q++)
      vv[q] = out1u[(size_t)(packed[j+q]&0xffff)*64 + lane];
    #pragma unroll
    for (int q=0;q<4;q++){
      a0 += bf2f((unsigned short)vv[q]);
      a1 += bf2f((unsigned short)(vv[q]>>16));
    }
  }
  for (; j<b1; ++j){
    unsigned int v = out1u[(size_t)(packed[j]&0xffff)*64 + lane];
    a0 += bf2f((unsigned short)v);
    a1 += bf2f((unsigned short)(v>>16));
  }
  agg2u[(size_t)node*64 + lane] = (unsigned int)f2bf(a0) | ((unsigned int)f2bf(a1) << 16);
}

// ---------------- head: logits + log_softmax ----------------
__global__ __launch_bounds__(256) void k_head(const unsigned short* __restrict__ hidden,
                                              const float* __restrict__ fc_w,
                                              const float* __restrict__ fc_b,
                                              float* __restrict__ out){
  int node = blockIdx.x*4 + (threadIdx.x >> 6);
  int lane = threadIdx.x & 63;
  if (node >= NN) return;
  float h0 = bf2f(hidden[(size_t)node*128 + lane*2]);
  float h1 = bf2f(hidden[(size_t)node*128 + lane*2 + 1]);
  float lg[CC];
  #pragma unroll
  for (int c=0;c<CC;c++){
    float p = h0*fc_w[(lane*2)*CC + c] + h1*fc_w[(lane*2+1)*CC + c];
    #pragma unroll
    for (int off=32; off; off>>=1) p += __shfl_down(p, off, 64);
    lg[c] = p;
  }
  if (lane == 0){
    float l[CC]; float m = -1e30f;
    #pragma unroll
    for (int c=0;c<CC;c++){ l[c] = lg[c] + fc_b[c]; m = fmaxf(m, l[c]); }
    float s = 0.f;
    #pragma unroll
    for (int c=0;c<CC;c++) s += expf(l[c]-m);
    float lse = logf(s);
    #pragma unroll
    for (int c=0;c<CC;c++) out[(size_t)node*CC + c] = l[c] - m - lse;
  }
}

extern "C" void kernel_launch(void* const* d_in, const int* in_sizes, int n_in,
                              void* d_out, int out_size, void* d_ws, size_t ws_size,
                              hipStream_t stream)
{
  const float* x      = (const float*)d_in[0];
  const int*   eidx   = (const int*)d_in[1];
  const int*   etype  = (const int*)d_in[3];
  const float* basis  = (const float*)d_in[8];
  const float* comp   = (const float*)d_in[9];
  const float* root1  = (const float*)d_in[10];
  const float* bias1  = (const float*)d_in[11];
  const float* w_rel  = (const float*)d_in[12];
  const float* w_root = (const float*)d_in[13];
  const float* bias2  = (const float*)d_in[14];
  const float* lin_w  = (const float*)d_in[15];
  const float* lin_b  = (const float*)d_in[16];
  const float* fc_w   = (const float*)d_in[17];
  const float* fc_b   = (const float*)d_in[18];
  const int* srcv = eidx;
  const int* dstv = eidx + EE;

  // workspace layout: total 248,316,416 B; A-source matrices padded to 50048 rows
  char* w = (char*)d_ws;
  unsigned short* x_bf    = (unsigned short*)(w + 0);                       // 50048*256*2
  unsigned short* xW      = (unsigned short*)(w + 25624576);                // 50000*2048*2 (dead after k_agg1)
  unsigned short* hidden  = (unsigned short*)(w + 25624576);                //  alias
  unsigned short* out2_bf = (unsigned short*)(w + 25624576 + 12812288);     //  alias (padded)
  unsigned short* agg2_bf = (unsigned short*)(w + 25624576 + 25624576);     //  alias (padded)
  unsigned short* WT      = (unsigned short*)(w + 230424576);               // 1,048,576
  unsigned short* rootT   = (unsigned short*)(w + 231473152);               // 65,536
  unsigned short* W2T     = (unsigned short*)(w + 231538688);               // 65,536
  unsigned short* linT    = (unsigned short*)(w + 231604224);               // 98,304
  unsigned short* out1_bf = (unsigned short*)(w + 231702528);               // 50048*128*2 (padded)
  int*            counts  = (int*)(w + 244514816);                          // 200,192
  int*            row_ptr = (int*)(w + 244715008);                          // 200,192
  int*            cursor  = (int*)(w + 244915200);                          // 200,192
  int*            packed  = (int*)(w + 245115392);                          // 3,200,000
  int*            blocksum= (int*)(w + 248315392);                          // 1,024

  hipMemsetAsync(counts, 0, NN*4, stream);
  hipMemsetAsync(cursor, 0, NN*4, stream);

  // prep
  k_cvt<<<12500, 256, 0, stream>>>(x, x_bf, NN*FF/4);
  k_build_wt<<<256, 256, 0, stream>>>(comp, basis, WT);
  k_transpose_cat<<<128, 256, 0, stream>>>(root1, 256, nullptr, 0, rootT);
  k_transpose_cat<<<128, 256, 0, stream>>>(w_rel, 128, w_root, 128, W2T);
  k_transpose_cat<<<192, 256, 0, stream>>>(lin_w, 384, nullptr, 0, linT);

  // CSR by dst
  k_count<<<3125, 256, 0, stream>>>(dstv, counts);
  k_scan1<<<196, 256, 0, stream>>>(counts, row_ptr, blocksum);
  k_scan2<<<1, 256, 0, stream>>>(blocksum, 196);
  k_scan3<<<196, 256, 0, stream>>>(row_ptr, blocksum);
  k_fill<<<3125, 256, 0, stream>>>(srcv, dstv, etype, row_ptr, cursor, packed);

  // GEMM1: xW = x_bf @ W  -> [N, 2048] bf16   (rasterized 1D grid: 391*16 = 6256)
  gemm_bt<false,false,true><<<6256, 256, 0, stream>>>(
      x_bf, FF, nullptr, 0, 1<<30, WT, xW, 2048, nullptr, NN, FF);
  // root: out1_bf = x_bf @ root1 + bias1  (bf16)
  {
    dim3 g(391, 1);
    gemm_bt<true,false,false><<<g, 256, 0, stream>>>(
        x_bf, FF, nullptr, 0, 1<<30, rootT, out1_bf, HH, bias1, NN, FF);
  }
  // RGCN aggregate: out1_bf += mean-per-(dst,rel) messages
  k_agg1<<<12500, 256, 0, stream>>>(row_ptr, packed, (const unsigned int*)xW, (unsigned int*)out1_bf);
  // GraphConv aggregate -> agg2_bf
  k_agg2<<<12500, 256, 0, stream>>>(row_ptr, packed, (const unsigned int*)out1_bf, (unsigned int*)agg2_bf);
  // GEMM2: out2 = [agg2 | out1] @ [w_rel; w_root] + bias2 -> bf16
  {
    dim3 g(391, 1);
    gemm_bt<true,false,false><<<g, 256, 0, stream>>>(
        agg2_bf, HH, out1_bf, HH, HH, W2T, out2_bf, HH, bias2, NN, 2*HH);
  }
  // GEMM3: hidden = relu([x | out2] @ lin_w + lin_b) -> bf16
  {
    dim3 g(391, 1);
    gemm_bt<true,true,false><<<g, 256, 0, stream>>>(
        x_bf, FF, out2_bf, HH, FF, linT, hidden, HH, lin_b, NN, FF+HH);
  }
  // head
  k_head<<<12500, 256, 0, stream>>>(hidden, fc_w, fc_b, (float*)d_out);
}